// Round 15
// baseline (88.546 us; speedup 1.0000x reference)
//
#include <hip/hip_runtime.h>
#include <hip/hip_bf16.h>

typedef short s16x8 __attribute__((ext_vector_type(8)));
typedef float f32x4 __attribute__((ext_vector_type(4)));

__device__ __forceinline__ unsigned short f2bf(float f) {
  union { __hip_bfloat16 h; unsigned short u; } cv;
  cv.h = __float2bfloat16(f);
  return cv.u;
}

__device__ __forceinline__ void gload_lds16(const void* g, void* l) {
  __builtin_amdgcn_global_load_lds(
      (const __attribute__((address_space(1))) unsigned int*)g,
      (__attribute__((address_space(3))) unsigned int*)l,
      16, 0, 0);
}

// Parallel exclusive scan of per-thread counts over 256 threads.
__device__ __forceinline__ int block_excl_scan(int cnt, int* wsum, int* total) {
  const int t = threadIdx.x;
  const int lane = t & 63, w = t >> 6;
  int x = cnt;
#pragma unroll
  for (int d = 1; d < 64; d <<= 1) {
    int y = __shfl_up(x, d);
    if (lane >= d) x += y;
  }
  if (lane == 63) wsum[w] = x;
  __syncthreads();
  int woff = 0;
#pragma unroll
  for (int i = 0; i < 4; ++i)
    if (i < w) woff += wsum[i];
  *total = wsum[0] + wsum[1] + wsum[2] + wsum[3];
  return woff + x - cnt;  // exclusive offset
}

// Fused: blocks [0,4096) gather H rows (local mask scan per block);
// blocks [4096,4104) write Lc/Lcp; blocks [4104,5128) cast G/Wk/Wq.
__global__ __launch_bounds__(256) void prep_gather(
    const float* __restrict__ H, const int* __restrict__ mask,
    int* __restrict__ Lc, int* __restrict__ Lcp,
    unsigned short* __restrict__ Hc, unsigned short* __restrict__ HcT,
    const float* __restrict__ G, unsigned short* __restrict__ Gbf,
    const float* __restrict__ Wk, unsigned short* __restrict__ Wkbf,
    const float* __restrict__ Wq, unsigned short* __restrict__ Wqbf) {
  const int t = threadIdx.x;
  const int flat = blockIdx.x;

  if (flat >= 4104) {  // ---- cast blocks ----
    const int cb = flat - 4104;
    const int n4a = 8 * 1024 * 768 / 4, n4b = 256 * 1024 / 4, n4c = 256 * 768 / 4;
    const int total = n4a + n4b + n4c;
    for (int i = cb * 256 + t; i < total; i += 1024 * 256) {
      const float* s; unsigned short* d; int j = i;
      if (j < n4a) { s = G; d = Gbf; }
      else if ((j -= n4a) < n4b) { s = Wk; d = Wkbf; }
      else { j -= n4b; s = Wq; d = Wqbf; }
      float4 v = *(const float4*)(s + (size_t)j * 4);
      ushort4 o;
      o.x = f2bf(v.x); o.y = f2bf(v.y); o.z = f2bf(v.z); o.w = f2bf(v.w);
      *(ushort4*)(d + (size_t)j * 4) = o;
    }
    return;
  }

  __shared__ int wsum[4];

  if (flat >= 4096) {  // ---- Lc/Lcp writeout blocks ----
    const int b = flat - 4096;
    const int* mb = mask + (size_t)b * 2048;
    int cnt = 0;
#pragma unroll
    for (int j = 0; j < 8; ++j) cnt += (mb[t * 8 + j] == 0);
    int total;
    block_excl_scan(cnt, wsum, &total);
    if (t == 0) {
      Lc[b] = total;
      Lcp[b] = (total + 127) & ~127;
    }
    return;
  }

  // ---- gather blocks: b XCD-spread, 512 per batch ----
  const int b = flat & 7;
  const int inner = flat >> 3;
  const int j0 = (inner & 31) * 64, d0 = (inner >> 5) * 64;

  const int* mb = mask + (size_t)b * 2048;
  int keep[8], cnt = 0;
#pragma unroll
  for (int j = 0; j < 8; ++j) {
    keep[j] = (mb[t * 8 + j] == 0);
    cnt += keep[j];
  }
  int total;
  int p = block_excl_scan(cnt, wsum, &total);
  const int lcp = (total + 127) & ~127;
  if (j0 >= lcp) return;
  const int lc = total;

  __shared__ int lidx[64];
#pragma unroll
  for (int j = 0; j < 8; ++j) {
    if (keep[j]) {
      if (p >= j0 && p < j0 + 64) lidx[p - j0] = t * 8 + j;
      ++p;
    }
  }
  __shared__ unsigned short tile[64][72];
  __syncthreads();

  const int r = t >> 2, dc = (t & 3) * 16;
  const int j = j0 + r;
  const int src = (j < lc) ? lidx[r] : -1;
  ushort4 s[4];
  if (src >= 0) {
    const float* pp = H + ((size_t)b * 2048 + src) * 1024 + d0 + dc;
#pragma unroll
    for (int i = 0; i < 4; ++i) {
      float4 v = *(const float4*)(pp + 4 * i);
      s[i].x = f2bf(v.x); s[i].y = f2bf(v.y); s[i].z = f2bf(v.z); s[i].w = f2bf(v.w);
    }
  } else {
#pragma unroll
    for (int i = 0; i < 4; ++i) { s[i].x = 0; s[i].y = 0; s[i].z = 0; s[i].w = 0; }
  }
  unsigned short* hcrow = Hc + ((size_t)b * 2048 + j) * 1024 + d0 + dc;
#pragma unroll
  for (int i = 0; i < 4; ++i) {
    *(ushort4*)&tile[r][dc + 4 * i] = s[i];
    *(ushort4*)(hcrow + 4 * i) = s[i];
  }
  __syncthreads();

  const int dr = t >> 2, lcc = (t & 3) * 16;
  unsigned short o[16];
#pragma unroll
  for (int i = 0; i < 16; ++i) o[i] = tile[lcc + i][dr];
  unsigned short* dst = HcT + ((size_t)b * 1024 + d0 + dr) * 2048 + j0 + lcc;
  *(uint4*)dst = *(uint4*)&o[0];
  *(uint4*)(dst + 8) = *(uint4*)&o[8];
}

// Shared GEMM core: C (128 x BN tile) = A * B^T, bf16 via global_load_lds.
// BK = 64, XOR-swizzled 16B slots (pre-swizzled global source + swizzled read).
// EPI 0: store bf16 scale*acc.
// EPI 1: store bf16 exp(scale*acc), zero at col>=lcv; per-block row sums.
// EPI 2: f32 store of scale*acc*inv(rowsum); inv from psumB in prologue.
template <int BN, int EPI, bool OUT_BF16>
__device__ __forceinline__ void gemm_core(
    unsigned short* As, unsigned short* Bs, float* redLds,
    const unsigned short* __restrict__ Abf, const unsigned short* __restrict__ Bbf,
    void* __restrict__ Cg_, int N, int K, int lda, int ldb, float scale,
    int bm, int bn, int lcv, float* __restrict__ psumOut,
    const float* __restrict__ psumB, int nb) {
  constexpr int NF = BN / 32;
  const int tid = threadIdx.x;
  const int l = tid & 63, wid = tid >> 6;
  const int wr = wid >> 1, wc = wid & 1;
  const int rowA0 = bm * 128, rowB0 = bn * BN;

  const int srow = l >> 3;                   // row within 8x8-slot chunk
  const int sslot = (l & 7) ^ (srow & 7);    // pre-swizzled global 16B slot
  const int soff = sslot * 8;

  if constexpr (EPI == 2) {
    if (tid < 128) {
      float s = 0.f;
      for (int j = 0; j < nb; ++j) s += psumB[(size_t)j * 1024 + tid];
      redLds[tid] = 1.0f / s;
    }
  }

  f32x4 acc[4][NF] = {};

  for (int k0 = 0; k0 < K; k0 += 64) {
#pragma unroll
    for (int i = 0; i < 4; ++i) {
      const int c = wid * 4 + i;
      gload_lds16(Abf + (size_t)(rowA0 + c * 8 + srow) * lda + k0 + soff,
                  &As[c * 512]);
    }
#pragma unroll
    for (int i = 0; i < BN / 32; ++i) {
      const int c = wid * (BN / 32) + i;
      gload_lds16(Bbf + (size_t)(rowB0 + c * 8 + srow) * ldb + k0 + soff,
                  &Bs[c * 512]);
    }
    __syncthreads();

    s16x8 af[4][2], bfr[NF][2];
#pragma unroll
    for (int m = 0; m < 4; ++m) {
      const int row = wr * 64 + m * 16 + (l & 15);
      const int rx = row & 7;
#pragma unroll
      for (int kk = 0; kk < 2; ++kk) {
        const int slot = kk * 4 + (l >> 4);
        af[m][kk] = *(const s16x8*)&As[row * 64 + (slot ^ rx) * 8];
      }
    }
#pragma unroll
    for (int n = 0; n < NF; ++n) {
      const int row = wc * (BN / 2) + n * 16 + (l & 15);
      const int rx = row & 7;
#pragma unroll
      for (int kk = 0; kk < 2; ++kk) {
        const int slot = kk * 4 + (l >> 4);
        bfr[n][kk] = *(const s16x8*)&Bs[row * 64 + (slot ^ rx) * 8];
      }
    }
#pragma unroll
    for (int kk = 0; kk < 2; ++kk)
#pragma unroll
      for (int m = 0; m < 4; ++m)
#pragma unroll
        for (int n = 0; n < NF; ++n)
          acc[m][n] = __builtin_amdgcn_mfma_f32_16x16x32_bf16(
              af[m][kk], bfr[n][kk], acc[m][n], 0, 0, 0);
    __syncthreads();
  }

  const int crow0 = bm * 128 + wr * 64, ccol0 = bn * BN + wc * (BN / 2);
  unsigned short* Cst = (unsigned short*)Cg_;
  float* Cf = (float*)Cg_;

  if constexpr (EPI == 1) {
    float (*psumLds)[128] = (float(*)[128])redLds;
    float rs[4][4];
#pragma unroll
    for (int m = 0; m < 4; ++m)
#pragma unroll
      for (int r = 0; r < 4; ++r) rs[m][r] = 0.f;
#pragma unroll
    for (int m = 0; m < 4; ++m) {
#pragma unroll
      for (int n = 0; n < NF; ++n) {
#pragma unroll
        for (int r = 0; r < 4; ++r) {
          const int row = crow0 + m * 16 + ((l >> 4) << 2) + r;
          const int col = ccol0 + n * 16 + (l & 15);
          const float e = (col < lcv) ? __expf(acc[m][n][r] * scale) : 0.f;
          rs[m][r] += e;
          Cst[(size_t)row * N + col] = f2bf(e);
        }
      }
    }
#pragma unroll
    for (int m = 0; m < 4; ++m)
#pragma unroll
      for (int r = 0; r < 4; ++r) {
#pragma unroll
        for (int off = 1; off < 16; off <<= 1)
          rs[m][r] += __shfl_xor(rs[m][r], off);
      }
    if ((l & 15) == 0) {
      const int q = l >> 4;
#pragma unroll
      for (int m = 0; m < 4; ++m)
#pragma unroll
        for (int r = 0; r < 4; ++r)
          psumLds[wc][wr * 64 + m * 16 + q * 4 + r] = rs[m][r];
    }
    __syncthreads();
    if (tid < 128)
      psumOut[tid] = psumLds[0][tid] + psumLds[1][tid];
  } else {
#pragma unroll
    for (int m = 0; m < 4; ++m) {
#pragma unroll
      for (int n = 0; n < NF; ++n) {
#pragma unroll
        for (int r = 0; r < 4; ++r) {
          const int rloc = wr * 64 + m * 16 + ((l >> 4) << 2) + r;
          const int row = bm * 128 + rloc;
          const int col = ccol0 + n * 16 + (l & 15);
          float val = acc[m][n][r] * scale;
          if constexpr (EPI == 2) val *= redLds[rloc];
          if constexpr (OUT_BF16)
            Cst[(size_t)row * N + col] = f2bf(val);
          else
            Cf[(size_t)row * N + col] = val;
        }
      }
    }
  }
}

// Merged K/Q projection: blocks [0,512) Kproj (batched XCD swizzle),
// blocks [512,768) Qproj (single-matrix XCD swizzle). Both 128x64 tiles.
__global__ __launch_bounds__(256) void gemm_kqproj(
    const unsigned short* __restrict__ Hc, const unsigned short* __restrict__ Wkbf,
    unsigned short* __restrict__ Kc,
    const unsigned short* __restrict__ Gbf, const unsigned short* __restrict__ Wqbf,
    unsigned short* __restrict__ Qbuf, const int* __restrict__ Lcp) {
  __shared__ unsigned short As[128 * 64];
  __shared__ unsigned short Bs[64 * 64];
  __shared__ float redLds[256];
  int x = blockIdx.x;
  const unsigned short *A_, *B_;
  unsigned short* C_;
  int K_, ld_, bm, bn;
  if (x < 512) {
    const int b = x & 7, inner = x >> 3;
    bm = inner >> 2; bn = inner & 3;
    if (bm * 128 >= Lcp[b]) return;
    A_ = Hc + (size_t)b * 2048 * 1024;
    B_ = Wkbf;
    C_ = Kc + (size_t)b * 2048 * 256;
    K_ = 1024; ld_ = 1024;
  } else {
    x -= 512;
    const int logical = (x & 7) * 32 + (x >> 3);
    bm = logical >> 2; bn = logical & 3;
    A_ = Gbf; B_ = Wqbf; C_ = Qbuf;
    K_ = 768; ld_ = 768;
  }
  gemm_core<64, 0, true>(As, Bs, redLds, A_, B_, C_, 256, K_, ld_, ld_, 1.0f,
                         bm, bn, 0, nullptr, nullptr, 0);
}

// Score: P' = exp(Q @ Kc^T * SCALE), zeroed at col>=Lc; per-block row sums.
__global__ __launch_bounds__(256) void gemm_score(
    const unsigned short* __restrict__ Qbuf, const unsigned short* __restrict__ Kc,
    unsigned short* __restrict__ Sbuf, const int* __restrict__ Lcp,
    const int* __restrict__ Lc, float* __restrict__ Psum) {
  __shared__ unsigned short As[128 * 64];
  __shared__ unsigned short Bs[128 * 64];
  __shared__ float redLds[256];
  const int b = blockIdx.x & 7, inner = blockIdx.x >> 3;
  const int bm = inner >> 4, bn = inner & 15;
  if (bn * 128 >= Lcp[b]) return;
  gemm_core<128, 1, true>(
      As, Bs, redLds,
      Qbuf + (size_t)b * 1024 * 256, Kc + (size_t)b * 2048 * 256,
      Sbuf + (size_t)b * 1024 * 2048, 2048, 256, 256, 256, 0.0625f,
      bm, bn, Lc[b], Psum + ((size_t)b * 16 + bn) * 1024 + bm * 128,
      nullptr, 0);
}

// PV: Z = (P' @ Hc) * inv(rowsum); inv computed in-block from Psum.
// 128x64 tiles -> 1024 blocks = 4 blocks/CU (16 waves/CU) for wave overlap.
__global__ __launch_bounds__(256) void gemm_pv(
    const unsigned short* __restrict__ Sbuf, const unsigned short* __restrict__ HcT,
    float* __restrict__ Z, const int* __restrict__ Lcp,
    const float* __restrict__ Psum) {
  __shared__ unsigned short As[128 * 64];
  __shared__ unsigned short Bs[64 * 64];
  __shared__ float redLds[256];
  const int b = blockIdx.x & 7, inner = blockIdx.x >> 3;  // inner 0..127
  const int bm = inner >> 4, bn = inner & 15;             // 8 x 16
  const int K = Lcp[b], nb = K >> 7;
  gemm_core<64, 2, false>(
      As, Bs, redLds,
      Sbuf + (size_t)b * 1024 * 2048, HcT + (size_t)b * 1024 * 2048,
      Z + (size_t)b * 1024 * 1024, 1024, K, 2048, 2048, 1.0f,
      bm, bn, 0, nullptr, Psum + (size_t)b * 16 * 1024 + bm * 128, nb);
}

extern "C" void kernel_launch(void* const* d_in, const int* in_sizes, int n_in,
                              void* d_out, int out_size, void* d_ws, size_t ws_size,
                              hipStream_t stream) {
  const float* H  = (const float*)d_in[0];   // (B, L, Dh)
  const float* G  = (const float*)d_in[1];   // (B, T, Dg)
  const int* mask = (const int*)d_in[2];     // (B, L), nonzero = masked
  const float* Wk = (const float*)d_in[3];   // (P, Dh)
  const float* Wq = (const float*)d_in[4];   // (P, Dg)
  float* Z = (float*)d_out;                  // (B, T, Dh)

  const size_t MiB = 1024 * 1024;
  char* ws = (char*)d_ws;
  unsigned short* HcT  = (unsigned short*)(ws);             // (B, Dh, L)  32 MiB
  unsigned short* Hc   = (unsigned short*)(ws + 32 * MiB);  // (B, L, Dh)  32 MiB
  unsigned short* Sbuf = Hc;  // alias: Hc dead after Kproj; holds P' = exp(S)
  unsigned short* Kc   = (unsigned short*)(ws + 64 * MiB);  // (B, L, P)    8 MiB
  unsigned short* Qbuf = (unsigned short*)(ws + 72 * MiB);  // (B, T, P)    4 MiB
  int* Lc  = (int*)(ws + 76 * MiB);
  int* Lcp = Lc + 16;
  unsigned short* Gbf  = (unsigned short*)(ws + 76 * MiB + 4096);  // 12 MiB
  unsigned short* Wkbf = (unsigned short*)(ws + 89 * MiB);         // 0.5 MiB
  unsigned short* Wqbf = (unsigned short*)(ws + 90 * MiB);         // 0.375 MiB
  float* PsumBuf = (float*)(ws + 91 * MiB);                        // 512 KiB

  // 1) fused: gather (local scans) + Lc/Lcp writeout + casts, one dispatch
  prep_gather<<<dim3(5128), 256, 0, stream>>>(
      H, mask, Lc, Lcp, Hc, HcT, G, Gbf, Wk, Wkbf, Wq, Wqbf);

  // 2) Kc = Hc @ Wk^T  and  Q = G @ Wq^T, one dispatch (768 blocks)
  gemm_kqproj<<<dim3(768), 256, 0, stream>>>(Hc, Wkbf, Kc, Gbf, Wqbf, Qbuf, Lcp);

  // 3) P' = exp(Q @ Kc^T * SCALE) + per-block row sums
  gemm_score<<<dim3(1024), 256, 0, stream>>>(Qbuf, Kc, Sbuf, Lcp, Lc, PsumBuf);

  // 4) Z = (P' @ Hc) * invRowSum, 128x64 tiles, 1024 blocks (4/CU)
  gemm_pv<<<dim3(1024), 256, 0, stream>>>(Sbuf, HcT, Z, Lcp, PsumBuf);
}

// Round 16
// 84.943 us; speedup vs baseline: 1.0424x; 1.0424x over previous
//
#include <hip/hip_runtime.h>
#include <hip/hip_bf16.h>

typedef short s16x8 __attribute__((ext_vector_type(8)));
typedef float f32x4 __attribute__((ext_vector_type(4)));

__device__ __forceinline__ unsigned short f2bf(float f) {
  union { __hip_bfloat16 h; unsigned short u; } cv;
  cv.h = __float2bfloat16(f);
  return cv.u;
}

__device__ __forceinline__ void gload_lds16(const void* g, void* l) {
  __builtin_amdgcn_global_load_lds(
      (const __attribute__((address_space(1))) unsigned int*)g,
      (__attribute__((address_space(3))) unsigned int*)l,
      16, 0, 0);
}

// Parallel exclusive scan of per-thread counts over 256 threads.
__device__ __forceinline__ int block_excl_scan(int cnt, int* wsum, int* total) {
  const int t = threadIdx.x;
  const int lane = t & 63, w = t >> 6;
  int x = cnt;
#pragma unroll
  for (int d = 1; d < 64; d <<= 1) {
    int y = __shfl_up(x, d);
    if (lane >= d) x += y;
  }
  if (lane == 63) wsum[w] = x;
  __syncthreads();
  int woff = 0;
#pragma unroll
  for (int i = 0; i < 4; ++i)
    if (i < w) woff += wsum[i];
  *total = wsum[0] + wsum[1] + wsum[2] + wsum[3];
  return woff + x - cnt;  // exclusive offset
}

// Fused: blocks [0,4096) gather H rows (local mask scan per block);
// blocks [4096,4104) write Lc/Lcp; blocks [4104,5128) cast G/Wk/Wq.
__global__ __launch_bounds__(256) void prep_gather(
    const float* __restrict__ H, const int* __restrict__ mask,
    int* __restrict__ Lc, int* __restrict__ Lcp,
    unsigned short* __restrict__ Hc, unsigned short* __restrict__ HcT,
    const float* __restrict__ G, unsigned short* __restrict__ Gbf,
    const float* __restrict__ Wk, unsigned short* __restrict__ Wkbf,
    const float* __restrict__ Wq, unsigned short* __restrict__ Wqbf) {
  const int t = threadIdx.x;
  const int flat = blockIdx.x;

  if (flat >= 4104) {  // ---- cast blocks ----
    const int cb = flat - 4104;
    const int n4a = 8 * 1024 * 768 / 4, n4b = 256 * 1024 / 4, n4c = 256 * 768 / 4;
    const int total = n4a + n4b + n4c;
    for (int i = cb * 256 + t; i < total; i += 1024 * 256) {
      const float* s; unsigned short* d; int j = i;
      if (j < n4a) { s = G; d = Gbf; }
      else if ((j -= n4a) < n4b) { s = Wk; d = Wkbf; }
      else { j -= n4b; s = Wq; d = Wqbf; }
      float4 v = *(const float4*)(s + (size_t)j * 4);
      ushort4 o;
      o.x = f2bf(v.x); o.y = f2bf(v.y); o.z = f2bf(v.z); o.w = f2bf(v.w);
      *(ushort4*)(d + (size_t)j * 4) = o;
    }
    return;
  }

  __shared__ int wsum[4];

  if (flat >= 4096) {  // ---- Lc/Lcp writeout blocks ----
    const int b = flat - 4096;
    const int* mb = mask + (size_t)b * 2048;
    int cnt = 0;
#pragma unroll
    for (int j = 0; j < 8; ++j) cnt += (mb[t * 8 + j] == 0);
    int total;
    block_excl_scan(cnt, wsum, &total);
    if (t == 0) {
      Lc[b] = total;
      Lcp[b] = (total + 127) & ~127;
    }
    return;
  }

  // ---- gather blocks: b XCD-spread, 512 per batch ----
  const int b = flat & 7;
  const int inner = flat >> 3;
  const int j0 = (inner & 31) * 64, d0 = (inner >> 5) * 64;

  const int* mb = mask + (size_t)b * 2048;
  int keep[8], cnt = 0;
#pragma unroll
  for (int j = 0; j < 8; ++j) {
    keep[j] = (mb[t * 8 + j] == 0);
    cnt += keep[j];
  }
  int total;
  int p = block_excl_scan(cnt, wsum, &total);
  const int lcp = (total + 127) & ~127;
  if (j0 >= lcp) return;
  const int lc = total;

  __shared__ int lidx[64];
#pragma unroll
  for (int j = 0; j < 8; ++j) {
    if (keep[j]) {
      if (p >= j0 && p < j0 + 64) lidx[p - j0] = t * 8 + j;
      ++p;
    }
  }
  __shared__ unsigned short tile[64][72];
  __syncthreads();

  const int r = t >> 2, dc = (t & 3) * 16;
  const int j = j0 + r;
  const int src = (j < lc) ? lidx[r] : -1;
  ushort4 s[4];
  if (src >= 0) {
    const float* pp = H + ((size_t)b * 2048 + src) * 1024 + d0 + dc;
#pragma unroll
    for (int i = 0; i < 4; ++i) {
      float4 v = *(const float4*)(pp + 4 * i);
      s[i].x = f2bf(v.x); s[i].y = f2bf(v.y); s[i].z = f2bf(v.z); s[i].w = f2bf(v.w);
    }
  } else {
#pragma unroll
    for (int i = 0; i < 4; ++i) { s[i].x = 0; s[i].y = 0; s[i].z = 0; s[i].w = 0; }
  }
  unsigned short* hcrow = Hc + ((size_t)b * 2048 + j) * 1024 + d0 + dc;
#pragma unroll
  for (int i = 0; i < 4; ++i) {
    *(ushort4*)&tile[r][dc + 4 * i] = s[i];
    *(ushort4*)(hcrow + 4 * i) = s[i];
  }
  __syncthreads();

  const int dr = t >> 2, lcc = (t & 3) * 16;
  unsigned short o[16];
#pragma unroll
  for (int i = 0; i < 16; ++i) o[i] = tile[lcc + i][dr];
  unsigned short* dst = HcT + ((size_t)b * 1024 + d0 + dr) * 2048 + j0 + lcc;
  *(uint4*)dst = *(uint4*)&o[0];
  *(uint4*)(dst + 8) = *(uint4*)&o[8];
}

// Shared GEMM core: C (128 x BN tile) = A * B^T, bf16 via global_load_lds.
// BK = 64, XOR-swizzled 16B slots (pre-swizzled global source + swizzled read).
// EPI 0: store bf16 scale*acc.
// EPI 1: store bf16 exp(scale*acc), zero at col>=lcv; per-block row sums.
// EPI 2: f32 store of scale*acc*inv(rowsum); inv from psumB in prologue.
template <int BN, int EPI, bool OUT_BF16>
__device__ __forceinline__ void gemm_core(
    unsigned short* As, unsigned short* Bs, float* redLds,
    const unsigned short* __restrict__ Abf, const unsigned short* __restrict__ Bbf,
    void* __restrict__ Cg_, int N, int K, int lda, int ldb, float scale,
    int bm, int bn, int lcv, float* __restrict__ psumOut,
    const float* __restrict__ psumB, int nb) {
  constexpr int NF = BN / 32;
  const int tid = threadIdx.x;
  const int l = tid & 63, wid = tid >> 6;
  const int wr = wid >> 1, wc = wid & 1;
  const int rowA0 = bm * 128, rowB0 = bn * BN;

  const int srow = l >> 3;                   // row within 8x8-slot chunk
  const int sslot = (l & 7) ^ (srow & 7);    // pre-swizzled global 16B slot
  const int soff = sslot * 8;

  if constexpr (EPI == 2) {
    if (tid < 128) {
      float s = 0.f;
      for (int j = 0; j < nb; ++j) s += psumB[(size_t)j * 1024 + tid];
      redLds[tid] = 1.0f / s;
    }
  }

  f32x4 acc[4][NF] = {};

  for (int k0 = 0; k0 < K; k0 += 64) {
#pragma unroll
    for (int i = 0; i < 4; ++i) {
      const int c = wid * 4 + i;
      gload_lds16(Abf + (size_t)(rowA0 + c * 8 + srow) * lda + k0 + soff,
                  &As[c * 512]);
    }
#pragma unroll
    for (int i = 0; i < BN / 32; ++i) {
      const int c = wid * (BN / 32) + i;
      gload_lds16(Bbf + (size_t)(rowB0 + c * 8 + srow) * ldb + k0 + soff,
                  &Bs[c * 512]);
    }
    __syncthreads();

    s16x8 af[4][2], bfr[NF][2];
#pragma unroll
    for (int m = 0; m < 4; ++m) {
      const int row = wr * 64 + m * 16 + (l & 15);
      const int rx = row & 7;
#pragma unroll
      for (int kk = 0; kk < 2; ++kk) {
        const int slot = kk * 4 + (l >> 4);
        af[m][kk] = *(const s16x8*)&As[row * 64 + (slot ^ rx) * 8];
      }
    }
#pragma unroll
    for (int n = 0; n < NF; ++n) {
      const int row = wc * (BN / 2) + n * 16 + (l & 15);
      const int rx = row & 7;
#pragma unroll
      for (int kk = 0; kk < 2; ++kk) {
        const int slot = kk * 4 + (l >> 4);
        bfr[n][kk] = *(const s16x8*)&Bs[row * 64 + (slot ^ rx) * 8];
      }
    }
#pragma unroll
    for (int kk = 0; kk < 2; ++kk)
#pragma unroll
      for (int m = 0; m < 4; ++m)
#pragma unroll
        for (int n = 0; n < NF; ++n)
          acc[m][n] = __builtin_amdgcn_mfma_f32_16x16x32_bf16(
              af[m][kk], bfr[n][kk], acc[m][n], 0, 0, 0);
    __syncthreads();
  }

  const int crow0 = bm * 128 + wr * 64, ccol0 = bn * BN + wc * (BN / 2);
  unsigned short* Cst = (unsigned short*)Cg_;
  float* Cf = (float*)Cg_;

  if constexpr (EPI == 1) {
    float (*psumLds)[128] = (float(*)[128])redLds;
    float rs[4][4];
#pragma unroll
    for (int m = 0; m < 4; ++m)
#pragma unroll
      for (int r = 0; r < 4; ++r) rs[m][r] = 0.f;
#pragma unroll
    for (int m = 0; m < 4; ++m) {
#pragma unroll
      for (int n = 0; n < NF; ++n) {
#pragma unroll
        for (int r = 0; r < 4; ++r) {
          const int row = crow0 + m * 16 + ((l >> 4) << 2) + r;
          const int col = ccol0 + n * 16 + (l & 15);
          const float e = (col < lcv) ? __expf(acc[m][n][r] * scale) : 0.f;
          rs[m][r] += e;
          Cst[(size_t)row * N + col] = f2bf(e);
        }
      }
    }
#pragma unroll
    for (int m = 0; m < 4; ++m)
#pragma unroll
      for (int r = 0; r < 4; ++r) {
#pragma unroll
        for (int off = 1; off < 16; off <<= 1)
          rs[m][r] += __shfl_xor(rs[m][r], off);
      }
    if ((l & 15) == 0) {
      const int q = l >> 4;
#pragma unroll
      for (int m = 0; m < 4; ++m)
#pragma unroll
        for (int r = 0; r < 4; ++r)
          psumLds[wc][wr * 64 + m * 16 + q * 4 + r] = rs[m][r];
    }
    __syncthreads();
    if (tid < 128)
      psumOut[tid] = psumLds[0][tid] + psumLds[1][tid];
  } else {
#pragma unroll
    for (int m = 0; m < 4; ++m) {
#pragma unroll
      for (int n = 0; n < NF; ++n) {
#pragma unroll
        for (int r = 0; r < 4; ++r) {
          const int rloc = wr * 64 + m * 16 + ((l >> 4) << 2) + r;
          const int row = bm * 128 + rloc;
          const int col = ccol0 + n * 16 + (l & 15);
          float val = acc[m][n][r] * scale;
          if constexpr (EPI == 2) val *= redLds[rloc];
          if constexpr (OUT_BF16)
            Cst[(size_t)row * N + col] = f2bf(val);
          else
            Cf[(size_t)row * N + col] = val;
        }
      }
    }
  }
}

// Merged K/Q projection: blocks [0,512) Kproj (batched XCD swizzle),
// blocks [512,768) Qproj (single-matrix XCD swizzle). Both 128x64 tiles.
__global__ __launch_bounds__(256) void gemm_kqproj(
    const unsigned short* __restrict__ Hc, const unsigned short* __restrict__ Wkbf,
    unsigned short* __restrict__ Kc,
    const unsigned short* __restrict__ Gbf, const unsigned short* __restrict__ Wqbf,
    unsigned short* __restrict__ Qbuf, const int* __restrict__ Lcp) {
  __shared__ unsigned short As[128 * 64];
  __shared__ unsigned short Bs[64 * 64];
  __shared__ float redLds[256];
  int x = blockIdx.x;
  const unsigned short *A_, *B_;
  unsigned short* C_;
  int K_, ld_, bm, bn;
  if (x < 512) {
    const int b = x & 7, inner = x >> 3;
    bm = inner >> 2; bn = inner & 3;
    if (bm * 128 >= Lcp[b]) return;
    A_ = Hc + (size_t)b * 2048 * 1024;
    B_ = Wkbf;
    C_ = Kc + (size_t)b * 2048 * 256;
    K_ = 1024; ld_ = 1024;
  } else {
    x -= 512;
    const int logical = (x & 7) * 32 + (x >> 3);
    bm = logical >> 2; bn = logical & 3;
    A_ = Gbf; B_ = Wqbf; C_ = Qbuf;
    K_ = 768; ld_ = 768;
  }
  gemm_core<64, 0, true>(As, Bs, redLds, A_, B_, C_, 256, K_, ld_, ld_, 1.0f,
                         bm, bn, 0, nullptr, nullptr, 0);
}

// Score: P' = exp(Q @ Kc^T * SCALE), zeroed at col>=Lc; per-block row sums.
__global__ __launch_bounds__(256) void gemm_score(
    const unsigned short* __restrict__ Qbuf, const unsigned short* __restrict__ Kc,
    unsigned short* __restrict__ Sbuf, const int* __restrict__ Lcp,
    const int* __restrict__ Lc, float* __restrict__ Psum) {
  __shared__ unsigned short As[128 * 64];
  __shared__ unsigned short Bs[128 * 64];
  __shared__ float redLds[256];
  const int b = blockIdx.x & 7, inner = blockIdx.x >> 3;
  const int bm = inner >> 4, bn = inner & 15;
  if (bn * 128 >= Lcp[b]) return;
  gemm_core<128, 1, true>(
      As, Bs, redLds,
      Qbuf + (size_t)b * 1024 * 256, Kc + (size_t)b * 2048 * 256,
      Sbuf + (size_t)b * 1024 * 2048, 2048, 256, 256, 256, 0.0625f,
      bm, bn, Lc[b], Psum + ((size_t)b * 16 + bn) * 1024 + bm * 128,
      nullptr, 0);
}

// PV: Z = (P' @ Hc) * inv(rowsum); inv computed in-block from Psum.
// 128x128 tiles, 512 blocks — empirical optimum (R4/R5/R7/R15 all worse).
__global__ __launch_bounds__(256) void gemm_pv(
    const unsigned short* __restrict__ Sbuf, const unsigned short* __restrict__ HcT,
    float* __restrict__ Z, const int* __restrict__ Lcp,
    const float* __restrict__ Psum) {
  __shared__ unsigned short As[128 * 64];
  __shared__ unsigned short Bs[128 * 64];
  __shared__ float redLds[256];
  const int b = blockIdx.x & 7, inner = blockIdx.x >> 3;
  const int bm = inner >> 3, bn = inner & 7;
  const int K = Lcp[b], nb = K >> 7;
  gemm_core<128, 2, false>(
      As, Bs, redLds,
      Sbuf + (size_t)b * 1024 * 2048, HcT + (size_t)b * 1024 * 2048,
      Z + (size_t)b * 1024 * 1024, 1024, K, 2048, 2048, 1.0f,
      bm, bn, 0, nullptr, Psum + (size_t)b * 16 * 1024 + bm * 128, nb);
}

extern "C" void kernel_launch(void* const* d_in, const int* in_sizes, int n_in,
                              void* d_out, int out_size, void* d_ws, size_t ws_size,
                              hipStream_t stream) {
  const float* H  = (const float*)d_in[0];   // (B, L, Dh)
  const float* G  = (const float*)d_in[1];   // (B, T, Dg)
  const int* mask = (const int*)d_in[2];     // (B, L), nonzero = masked
  const float* Wk = (const float*)d_in[3];   // (P, Dh)
  const float* Wq = (const float*)d_in[4];   // (P, Dg)
  float* Z = (float*)d_out;                  // (B, T, Dh)

  const size_t MiB = 1024 * 1024;
  char* ws = (char*)d_ws;
  unsigned short* HcT  = (unsigned short*)(ws);             // (B, Dh, L)  32 MiB
  unsigned short* Hc   = (unsigned short*)(ws + 32 * MiB);  // (B, L, Dh)  32 MiB
  unsigned short* Sbuf = Hc;  // alias: Hc dead after Kproj; holds P' = exp(S)
  unsigned short* Kc   = (unsigned short*)(ws + 64 * MiB);  // (B, L, P)    8 MiB
  unsigned short* Qbuf = (unsigned short*)(ws + 72 * MiB);  // (B, T, P)    4 MiB
  int* Lc  = (int*)(ws + 76 * MiB);
  int* Lcp = Lc + 16;
  unsigned short* Gbf  = (unsigned short*)(ws + 76 * MiB + 4096);  // 12 MiB
  unsigned short* Wkbf = (unsigned short*)(ws + 89 * MiB);         // 0.5 MiB
  unsigned short* Wqbf = (unsigned short*)(ws + 90 * MiB);         // 0.375 MiB
  float* PsumBuf = (float*)(ws + 91 * MiB);                        // 512 KiB

  // 1) fused: gather (local scans) + Lc/Lcp writeout + casts, one dispatch
  prep_gather<<<dim3(5128), 256, 0, stream>>>(
      H, mask, Lc, Lcp, Hc, HcT, G, Gbf, Wk, Wkbf, Wq, Wqbf);

  // 2) Kc = Hc @ Wk^T  and  Q = G @ Wq^T, one dispatch (768 blocks)
  gemm_kqproj<<<dim3(768), 256, 0, stream>>>(Hc, Wkbf, Kc, Gbf, Wqbf, Qbuf, Lcp);

  // 3) P' = exp(Q @ Kc^T * SCALE) + per-block row sums
  gemm_score<<<dim3(1024), 256, 0, stream>>>(Qbuf, Kc, Sbuf, Lcp, Lc, PsumBuf);

  // 4) Z = (P' @ Hc) * invRowSum  (inv folded into PV prologue)
  gemm_pv<<<dim3(512), 256, 0, stream>>>(Sbuf, HcT, Z, Lcp, PsumBuf);
}